// Round 4
// baseline (8676.614 us; speedup 1.0000x reference)
//
#include <hip/hip_runtime.h>
#include <cfloat>
#include <cmath>

#define NROWS 32768
#define NTOK  8192
#define DIM   768
#define KSPLIT 384   // OpenBLAS sgemm kc (SGEMM_DEFAULT_Q, zen/haswell) — K=768 -> 2 chains

#define BM 64
#define BN 128
#define BK 32
#define NT 512

// float offsets in d_out (concatenated outputs, all read back as f32)
#define Q_OFF   0
#define EI_OFF  (NROWS*DIM)          // 25165824
#define TV_OFF  (EI_OFF + NROWS)     // 25198592
#define TI_OFF  (TV_OFF + NROWS*3)   // 25296896

// ---------------------------------------------------------------- numpy-exact row sum of squares
// numpy pairwise_sum, n=768: 768->384+384->192+192 each->96-blocks (8 accumulators,
// 12 adds each, combined ((r0+r1)+(r2+r3))+((r4+r5)+(r6+r7))), then binary tree.
// lane = 8*blk + j; butterfly m=1,2,4 = in-block combine; m=8,16,32 = block tree.
// contract OFF so squares round before adds (numpy materializes x**2 first).
__global__ __launch_bounds__(256)
void np_norm_kernel(const float* __restrict__ x, float* __restrict__ o) {
#pragma clang fp contract(off)
  const int wid = (blockIdx.x * 256 + threadIdx.x) >> 6;  // one wave per row
  const int lane = threadIdx.x & 63;
  const float* p = x + (size_t)wid * DIM + (lane >> 3) * 96 + (lane & 7);
  float v = p[0];
  float r = v * v;
#pragma unroll
  for (int k = 1; k < 12; k++) {
    float w = p[8 * k];
    float sq = w * w;
    r = r + sq;
  }
#pragma unroll
  for (int m = 1; m < 64; m <<= 1) {
    float other = __shfl_xor(r, m, 64);
    r = r + other;
  }
  if (lane == 0) o[wid] = r;
}

// ---------------------------------------------------------------- top-4 helpers (fp32 key, index tie-break)
__device__ __forceinline__ bool dless(float a, int ai, float b, int bi_) {
  return (a < b) || (a == b && ai < bi_);
}

__device__ __forceinline__ void ins4(float (&v)[4], int (&x)[4], float c, int ci) {
  if (dless(c, ci, v[3], x[3])) {
    v[3] = c; x[3] = ci;
    if (dless(v[3], x[3], v[2], x[2])) { float tv = v[2]; int ti = x[2]; v[2] = v[3]; x[2] = x[3]; v[3] = tv; x[3] = ti; }
    if (dless(v[2], x[2], v[1], x[1])) { float tv = v[1]; int ti = x[1]; v[1] = v[2]; x[1] = x[2]; v[2] = tv; x[2] = ti; }
    if (dless(v[1], x[1], v[0], x[0])) { float tv = v[0]; int ti = x[0]; v[0] = v[1]; x[0] = x[1]; v[1] = tv; x[1] = ti; }
  }
}

// ---------------------------------------------------------------- fused GEMM + top-4 + outputs
__global__ __launch_bounds__(NT, 4)
void vq_main(const float* __restrict__ A, const float* __restrict__ E,
             const float* __restrict__ x2, const float* __restrict__ e2,
             float* __restrict__ out) {
  __shared__ float a_s[BK][BM + 4];
  __shared__ float b_s[BK][BN + 4];

  const int tid = threadIdx.x;
  const int tx = tid & 15;   // column group: cols tx*8 .. tx*8+7
  const int ty = tid >> 4;   // row group:    rows ty*2 .. ty*2+1
  const int row0 = blockIdx.x * BM;

  const float x2r[2] = { x2[row0 + ty * 2 + 0], x2[row0 + ty * 2 + 1] };

  float bv[2][4];
  int   bi[2][4];
#pragma unroll
  for (int i = 0; i < 2; i++)
#pragma unroll
    for (int c = 0; c < 4; c++) { bv[i][c] = FLT_MAX; bi[i][c] = 0x7FFFFFFF; }

  // one K-block stage+compute step: stages [k0,k0+BK) and accumulates into ACC
#define GEMM_STEP(k0, ACC)                                                       \
    {                                                                            \
      __syncthreads();                                                           \
      {                                                                          \
        const int r = tid >> 3, kq = tid & 7;                                    \
        const float4 v = *(const float4*)(A + (size_t)(row0 + r) * DIM + (k0 + kq * 4)); \
        a_s[kq * 4 + 0][r] = v.x; a_s[kq * 4 + 1][r] = v.y;                      \
        a_s[kq * 4 + 2][r] = v.z; a_s[kq * 4 + 3][r] = v.w;                      \
        _Pragma("unroll")                                                        \
        for (int s = 0; s < 2; s++) {                                            \
          const int fi = tid + s * NT;                                           \
          const int rb = fi >> 3, kb = fi & 7;                                   \
          const float4 w = *(const float4*)(E + (size_t)(col0 + rb) * DIM + (k0 + kb * 4)); \
          b_s[kb * 4 + 0][rb] = w.x; b_s[kb * 4 + 1][rb] = w.y;                  \
          b_s[kb * 4 + 2][rb] = w.z; b_s[kb * 4 + 3][rb] = w.w;                  \
        }                                                                        \
      }                                                                          \
      __syncthreads();                                                           \
      _Pragma("unroll")                                                          \
      for (int k = 0; k < BK; k++) {                                             \
        const float2 a2 = *(const float2*)&a_s[k][ty * 2];                       \
        float br[8];                                                             \
        *(float4*)(br)     = *(const float4*)&b_s[k][tx * 8];                    \
        *(float4*)(br + 4) = *(const float4*)&b_s[k][tx * 8 + 4];                \
        _Pragma("unroll")                                                        \
        for (int j = 0; j < 8; j++) {                                            \
          ACC[0][j] = fmaf(a2.x, br[j], ACC[0][j]);                              \
          ACC[1][j] = fmaf(a2.y, br[j], ACC[1][j]);                              \
        }                                                                        \
      }                                                                          \
    }

  for (int ct = 0; ct < NTOK / BN; ++ct) {
    const int col0 = ct * BN;

    // two fp32 chains per element, split at k=KSPLIT (BLAS kc blocking),
    // each sequential-fma ascending-k from zero, combined with one add.
    float accA[2][8], accB[2][8];
#pragma unroll
    for (int i = 0; i < 2; i++)
#pragma unroll
      for (int j = 0; j < 8; j++) { accA[i][j] = 0.f; accB[i][j] = 0.f; }

    for (int k0 = 0; k0 < KSPLIT; k0 += BK) GEMM_STEP(k0, accA)
    for (int k0 = KSPLIT; k0 < DIM; k0 += BK) GEMM_STEP(k0, accB)

    // d = fl( fl(x2 + e2) - 2*fl(accA+accB) )  — numpy's exact evaluation order
    float e2v[8];
    *(float4*)(e2v)     = *(const float4*)(e2 + col0 + tx * 8);
    *(float4*)(e2v + 4) = *(const float4*)(e2 + col0 + tx * 8 + 4);
#pragma unroll
    for (int i = 0; i < 2; i++) {
#pragma unroll
      for (int j = 0; j < 8; j++) {
        const float dot = accA[i][j] + accB[i][j];
        const float se = x2r[i] + e2v[j];
        const float d = fmaf(-2.0f, dot, se);   // == fl(se - 2*dot), 2*dot exact
        const int ci = col0 + tx * 8 + j;
        ins4(bv[i], bi[i], d, ci);
      }
    }
  }
#undef GEMM_STEP

  // butterfly-merge top-4 across the 16 lanes sharing each row pair
#pragma unroll
  for (int m = 1; m < 16; m <<= 1) {
#pragma unroll
    for (int i = 0; i < 2; i++) {
      float ov[4]; int oi[4];
#pragma unroll
      for (int c = 0; c < 4; c++) {
        ov[c] = __shfl_xor(bv[i][c], m, 64);
        oi[c] = __shfl_xor(bi[i][c], m, 64);
      }
#pragma unroll
      for (int c = 0; c < 4; c++) ins4(bv[i], bi[i], ov[c], oi[c]);
    }
  }

  // scalar epilogue: lane tx==i handles row ty*2+i
#pragma unroll
  for (int i = 0; i < 2; i++) {
    if (tx == i) {
      const int gr = row0 + ty * 2 + i;
      out[EI_OFF + gr] = (float)bi[i][0];
      const double d1 = (double)bv[i][1], d2 = (double)bv[i][2], d3 = (double)bv[i][3];
      double nrm = sqrt(d1 * d1 + d2 * d2 + d3 * d3);
      nrm = fmax(nrm, 1e-12);
      const double t1 = 1.0 / (d1 / nrm + 1e-4);
      const double t2 = 1.0 / (d2 / nrm + 1e-4);
      const double t3 = 1.0 / (d3 / nrm + 1e-4);
      const double mx = fmax(t1, fmax(t2, t3));
      const double e1 = exp(t1 - mx), e2x = exp(t2 - mx), e3 = exp(t3 - mx);
      const double s = e1 + e2x + e3;
      out[TV_OFF + gr * 3 + 0] = (float)(e1 / s);
      out[TV_OFF + gr * 3 + 1] = (float)(e2x / s);
      out[TV_OFF + gr * 3 + 2] = (float)(e3 / s);
      out[TI_OFF + gr * 3 + 0] = (float)bi[i][1];
      out[TI_OFF + gr * 3 + 1] = (float)bi[i][2];
      out[TI_OFF + gr * 3 + 2] = (float)bi[i][3];
    }
  }

  // broadcast argmin index per local row through LDS, then copy quantize rows
  __syncthreads();
  int* idx_sh = (int*)&a_s[0][0];
  if (tx == 0) idx_sh[ty * 2 + 0] = bi[0][0];
  if (tx == 1) idx_sh[ty * 2 + 1] = bi[1][0];
  __syncthreads();

  for (int f = tid; f < BM * (DIM / 4); f += NT) {
    const int r = f / (DIM / 4);
    const int c = f % (DIM / 4);
    const int e = idx_sh[r];
    const float4 v = *(const float4*)(E + (size_t)e * DIM + c * 4);
    *(float4*)(out + Q_OFF + (size_t)(row0 + r) * DIM + c * 4) = v;
  }
}

// ---------------------------------------------------------------- launch
extern "C" void kernel_launch(void* const* d_in, const int* in_sizes, int n_in,
                              void* d_out, int out_size, void* d_ws, size_t ws_size,
                              hipStream_t stream) {
  const float* x = (const float*)d_in[0];  // inputs_flatten [32768,768]
  const float* E = (const float*)d_in[1];  // embed          [8192,768]
  float* out = (float*)d_out;

  float* e2 = (float*)d_ws;        // 8192 floats
  float* x2 = e2 + NTOK;           // 32768 floats

  np_norm_kernel<<<NTOK / 4, 256, 0, stream>>>(E, e2);
  np_norm_kernel<<<NROWS / 4, 256, 0, stream>>>(x, x2);
  vq_main<<<NROWS / BM, NT, 0, stream>>>(x, E, x2, e2, out);
}

// Round 5
// 1897.895 us; speedup vs baseline: 4.5717x; 4.5717x over previous
//
#include <hip/hip_runtime.h>
#include <cfloat>
#include <cmath>

#define NROWS 32768
#define NTOK  8192
#define DIM   768
#define KSPLIT 384   // OpenBLAS sgemm kc — K=768 -> two sequential fp32 chains (verified R4)

// fallback (R4) tiling
#define BM 64
#define BN 128
#define BK 32
#define NT 512

// float offsets in d_out (concatenated outputs, all read back as f32)
#define Q_OFF   0
#define EI_OFF  (NROWS*DIM)          // 25165824
#define TV_OFF  (EI_OFF + NROWS)     // 25198592
#define TI_OFF  (TV_OFF + NROWS*3)   // 25296896

typedef short short8 __attribute__((ext_vector_type(8)));
typedef float f32x4 __attribute__((ext_vector_type(4)));

// ---------------------------------------------------------------- numpy-exact row sum of squares
// (verified bit-exact in R4 — do not touch)
__global__ __launch_bounds__(256)
void np_norm_kernel(const float* __restrict__ x, float* __restrict__ o) {
#pragma clang fp contract(off)
  const int wid = (blockIdx.x * 256 + threadIdx.x) >> 6;  // one wave per row
  const int lane = threadIdx.x & 63;
  const float* p = x + (size_t)wid * DIM + (lane >> 3) * 96 + (lane & 7);
  float v = p[0];
  float r = v * v;
#pragma unroll
  for (int k = 1; k < 12; k++) {
    float w = p[8 * k];
    float sq = w * w;
    r = r + sq;
  }
#pragma unroll
  for (int m = 1; m < 64; m <<= 1) {
    float other = __shfl_xor(r, m, 64);
    r = r + other;
  }
  if (lane == 0) o[wid] = r;
}

// ---------------------------------------------------------------- helpers
__device__ __forceinline__ bool dless(float a, int ai, float b, int bi_) {
  return (a < b) || (a == b && ai < bi_);
}

__device__ __forceinline__ void ins4(float (&v)[4], int (&x)[4], float c, int ci) {
  if (dless(c, ci, v[3], x[3])) {
    v[3] = c; x[3] = ci;
    if (dless(v[3], x[3], v[2], x[2])) { float tv = v[2]; int ti = x[2]; v[2] = v[3]; x[2] = x[3]; v[3] = tv; x[3] = ti; }
    if (dless(v[2], x[2], v[1], x[1])) { float tv = v[1]; int ti = x[1]; v[1] = v[2]; x[1] = x[2]; v[2] = tv; x[2] = ti; }
    if (dless(v[1], x[1], v[0], x[0])) { float tv = v[0]; int ti = x[0]; v[0] = v[1]; x[0] = x[1]; v[1] = tv; x[1] = ti; }
  }
}

__device__ __forceinline__ void ins8(float (&v)[8], int (&x)[8], float c, int ci) {
  if (dless(c, ci, v[7], x[7])) {
    v[7] = c; x[7] = ci;
#pragma unroll
    for (int k = 7; k > 0; k--) {
      if (dless(v[k], x[k], v[k - 1], x[k - 1])) {
        float tv = v[k - 1]; int ti = x[k - 1];
        v[k - 1] = v[k]; x[k - 1] = x[k];
        v[k] = tv; x[k] = ti;
      }
    }
  }
}

__device__ __forceinline__ unsigned short f2bf(float f) {  // RNE fp32 -> bf16
  unsigned int u = __float_as_uint(f);
  u += 0x7FFFu + ((u >> 16) & 1u);
  return (unsigned short)(u >> 16);
}

// ---------------------------------------------------------------- bf16 pre-convert
__global__ __launch_bounds__(256)
void cvt_bf16_kernel(const float* __restrict__ in, unsigned short* __restrict__ out, int n4) {
  for (int i = blockIdx.x * 256 + threadIdx.x; i < n4; i += gridDim.x * 256) {
    const float4 v = ((const float4*)in)[i];
    ushort4 o;
    o.x = f2bf(v.x); o.y = f2bf(v.y); o.z = f2bf(v.z); o.w = f2bf(v.w);
    ((ushort4*)out)[i] = o;
  }
}

// ---------------------------------------------------------------- stage 1: MFMA rank -> top-8 candidates per row
// block: 512 thr (8 waves, 2 wm x 4 wn), tile 128 rows x 256 cols, BK=32, mfma 16x16x32 bf16
#define BN2 256
#define A_PLANE 2064   // 128*16 + 16 pad
#define B_PLANE 4112   // 256*16 + 16 pad
__global__ __launch_bounds__(512, 2)
void vq_rank(const unsigned short* __restrict__ xb, const unsigned short* __restrict__ eb,
             const float* __restrict__ e2, int* __restrict__ topi) {
  __shared__ __align__(16) unsigned char a_raw[4 * A_PLANE];
  __shared__ __align__(16) unsigned char b_raw[4 * B_PLANE];
  __shared__ __align__(16) float s_lds[128 * 68];  // [row][c(16)][j(4)] + pad; reused for final merge

  const int tid = threadIdx.x;
  const int lane = tid & 63;
  const int wave = tid >> 6;
  const int wm = wave >> 2;   // 0..1
  const int wn = wave & 3;    // 0..3
  const int row0 = blockIdx.x * 128;
  const int l15 = lane & 15, l4 = lane >> 4;

  // persistent top-8: thread owns row (tid>>2), col-subset (tid&3)
  float bv[8]; int bi[8];
#pragma unroll
  for (int c = 0; c < 8; c++) { bv[c] = FLT_MAX; bi[c] = 0x7FFFFFFF; }

  for (int ct = 0; ct < NTOK / BN2; ++ct) {
    const int col0 = ct * BN2;
    f32x4 acc[4][4];
#pragma unroll
    for (int i = 0; i < 4; i++)
#pragma unroll
      for (int j = 0; j < 4; j++) acc[i][j] = (f32x4)0.f;

    for (int ks = 0; ks < DIM / 32; ++ks) {
      const int k0 = ks * 32;
      __syncthreads();
      {
        // A: 128 rows x 32 k = 512 x (8 bf16); one 16B chunk per thread
        const int ar = tid >> 2, akb = tid & 3;
        *(int4*)(a_raw + akb * A_PLANE + ar * 16) =
            *(const int4*)(xb + (size_t)(row0 + ar) * DIM + k0 + akb * 8);
        // B: 256 cols x 32 k = 1024 chunks; two per thread
#pragma unroll
        for (int s = 0; s < 2; s++) {
          const int f = tid + s * 512;
          const int bc = f >> 2, bkb = f & 3;
          *(int4*)(b_raw + bkb * B_PLANE + bc * 16) =
              *(const int4*)(eb + (size_t)(col0 + bc) * DIM + k0 + bkb * 8);
        }
      }
      __syncthreads();
      short8 af[4], bf[4];
#pragma unroll
      for (int i = 0; i < 4; i++)
        af[i] = *(const short8*)(a_raw + l4 * A_PLANE + (wm * 64 + i * 16 + l15) * 16);
#pragma unroll
      for (int j = 0; j < 4; j++)
        bf[j] = *(const short8*)(b_raw + l4 * B_PLANE + (wn * 64 + j * 16 + l15) * 16);
#pragma unroll
      for (int i = 0; i < 4; i++)
#pragma unroll
        for (int j = 0; j < 4; j++)
          acc[i][j] = __builtin_amdgcn_mfma_f32_16x16x32_bf16(af[i], bf[j], acc[i][j], 0, 0, 0);
    }

    // selection: 4 phases (one per wn-group), s = e2[col] - 2*dot (row-const x2 omitted: rank-invariant)
#pragma unroll 1
    for (int p = 0; p < 4; ++p) {
      __syncthreads();
      if (wn == p) {
        float e2v[4];
#pragma unroll
        for (int j = 0; j < 4; j++) e2v[j] = e2[col0 + p * 64 + j * 16 + l15];
#pragma unroll
        for (int i = 0; i < 4; i++)
#pragma unroll
          for (int reg = 0; reg < 4; reg++) {
            const int row_rel = wm * 64 + i * 16 + l4 * 4 + reg;
            float4 s4;
            s4.x = fmaf(-2.f, acc[i][0][reg], e2v[0]);
            s4.y = fmaf(-2.f, acc[i][1][reg], e2v[1]);
            s4.z = fmaf(-2.f, acc[i][2][reg], e2v[2]);
            s4.w = fmaf(-2.f, acc[i][3][reg], e2v[3]);
            *(float4*)(s_lds + row_rel * 68 + l15 * 4) = s4;
          }
      }
      __syncthreads();
      const int srow = tid >> 2, q = tid & 3;
#pragma unroll
      for (int cc = 0; cc < 4; ++cc) {
        const int c = q * 4 + cc;
        const float4 v = *(const float4*)(s_lds + srow * 68 + c * 4);
        const int cb = col0 + p * 64 + c;
        ins8(bv, bi, v.x, cb);
        ins8(bv, bi, v.y, cb + 16);
        ins8(bv, bi, v.z, cb + 32);
        ins8(bv, bi, v.w, cb + 48);
      }
    }
  }

  // final 4-way merge (4 threads per row) via s_lds
  __syncthreads();
  {
    float* slot = s_lds + tid * 16;
#pragma unroll
    for (int c = 0; c < 8; c++) { slot[c] = bv[c]; slot[8 + c] = __int_as_float(bi[c]); }
  }
  __syncthreads();
  if ((tid & 3) == 0) {
#pragma unroll
    for (int o = 1; o < 4; o++) {
      const float* os = s_lds + (tid + o) * 16;
#pragma unroll
      for (int c = 0; c < 8; c++) ins8(bv, bi, os[c], __float_as_int(os[8 + c]));
    }
    const int row = row0 + (tid >> 2);
#pragma unroll
    for (int c = 0; c < 8; c++) topi[(size_t)row * 8 + c] = bi[c];
  }
}

// ---------------------------------------------------------------- stage 2: exact fp32 refine (replicates R4 arithmetic)
__global__ __launch_bounds__(256)
void vq_refine(const float* __restrict__ x, const float* __restrict__ E,
               const float* __restrict__ x2, const float* __restrict__ e2,
               const int* __restrict__ topi, float* __restrict__ out) {
  const int tg = blockIdx.x * 256 + threadIdx.x;
  const int row = tg >> 3;
  const int slot = tg & 7;
  const int myc = topi[(size_t)row * 8 + slot];

  const float4* xr = (const float4*)(x + (size_t)row * DIM);
  const float4* er = (const float4*)(E + (size_t)myc * DIM);
  // two sequential fp32 fma chains split at k=KSPLIT, ascending — identical to R4's GEMM per-element chain
  float accA = 0.f, accB = 0.f;
#pragma unroll 8
  for (int q = 0; q < KSPLIT / 4; ++q) {
    const float4 a = xr[q], b = er[q];
    accA = fmaf(a.x, b.x, accA); accA = fmaf(a.y, b.y, accA);
    accA = fmaf(a.z, b.z, accA); accA = fmaf(a.w, b.w, accA);
  }
#pragma unroll 8
  for (int q = KSPLIT / 4; q < DIM / 4; ++q) {
    const float4 a = xr[q], b = er[q];
    accB = fmaf(a.x, b.x, accB); accB = fmaf(a.y, b.y, accB);
    accB = fmaf(a.z, b.z, accB); accB = fmaf(a.w, b.w, accB);
  }
  const float dot = accA + accB;
  const float se = x2[row] + e2[myc];
  const float d = fmaf(-2.0f, dot, se);

  // gather the 8 candidates of this row within the 8-lane group
  const int base = (threadIdx.x & 63) & ~7;
  float dv[8]; int civ[8];
#pragma unroll
  for (int s = 0; s < 8; s++) {
    dv[s] = __shfl(d, base + s, 64);
    civ[s] = __shfl(myc, base + s, 64);
  }
  // exact ascending sort with index tie-break (uniform across lanes)
#pragma unroll
  for (int a = 0; a < 7; a++)
#pragma unroll
    for (int b = 7; b > 0; b--) {
      const bool sw = (dv[b] < dv[b - 1]) || (dv[b] == dv[b - 1] && civ[b] < civ[b - 1]);
      if (sw) {
        float td = dv[b]; dv[b] = dv[b - 1]; dv[b - 1] = td;
        int ti = civ[b]; civ[b] = civ[b - 1]; civ[b - 1] = ti;
      }
    }

  const int l8 = threadIdx.x & 7;
  if (l8 == 0) {
    out[EI_OFF + row] = (float)civ[0];
    const double d1 = (double)dv[1], d2 = (double)dv[2], d3 = (double)dv[3];
    double nrm = sqrt(d1 * d1 + d2 * d2 + d3 * d3);
    nrm = fmax(nrm, 1e-12);
    const double t1 = 1.0 / (d1 / nrm + 1e-4);
    const double t2 = 1.0 / (d2 / nrm + 1e-4);
    const double t3 = 1.0 / (d3 / nrm + 1e-4);
    const double mx = fmax(t1, fmax(t2, t3));
    const double e1 = exp(t1 - mx), e2x = exp(t2 - mx), e3 = exp(t3 - mx);
    const double s = e1 + e2x + e3;
    out[TV_OFF + row * 3 + 0] = (float)(e1 / s);
    out[TV_OFF + row * 3 + 1] = (float)(e2x / s);
    out[TV_OFF + row * 3 + 2] = (float)(e3 / s);
    out[TI_OFF + row * 3 + 0] = (float)civ[1];
    out[TI_OFF + row * 3 + 1] = (float)civ[2];
    out[TI_OFF + row * 3 + 2] = (float)civ[3];
  }

  // quantize = embed[argmin]: 8-lane cooperative float4 copy
  const float4* src = (const float4*)(E + (size_t)civ[0] * DIM);
  float4* dst = (float4*)(out + Q_OFF + (size_t)row * DIM);
#pragma unroll
  for (int it = 0; it < 24; ++it) dst[l8 + it * 8] = src[l8 + it * 8];
}

// ---------------------------------------------------------------- fallback: R4's passing fused fp32 kernel (verbatim)
__global__ __launch_bounds__(NT, 4)
void vq_main(const float* __restrict__ A, const float* __restrict__ E,
             const float* __restrict__ x2, const float* __restrict__ e2,
             float* __restrict__ out) {
  __shared__ float a_s[BK][BM + 4];
  __shared__ float b_s[BK][BN + 4];

  const int tid = threadIdx.x;
  const int tx = tid & 15;
  const int ty = tid >> 4;
  const int row0 = blockIdx.x * BM;

  const float x2r[2] = { x2[row0 + ty * 2 + 0], x2[row0 + ty * 2 + 1] };

  float bv[2][4];
  int   bi[2][4];
#pragma unroll
  for (int i = 0; i < 2; i++)
#pragma unroll
    for (int c = 0; c < 4; c++) { bv[i][c] = FLT_MAX; bi[i][c] = 0x7FFFFFFF; }

#define GEMM_STEP(k0, ACC)                                                       \
    {                                                                            \
      __syncthreads();                                                           \
      {                                                                          \
        const int r = tid >> 3, kq = tid & 7;                                    \
        const float4 v = *(const float4*)(A + (size_t)(row0 + r) * DIM + (k0 + kq * 4)); \
        a_s[kq * 4 + 0][r] = v.x; a_s[kq * 4 + 1][r] = v.y;                      \
        a_s[kq * 4 + 2][r] = v.z; a_s[kq * 4 + 3][r] = v.w;                      \
        _Pragma("unroll")                                                        \
        for (int s = 0; s < 2; s++) {                                            \
          const int fi = tid + s * NT;                                           \
          const int rb = fi >> 3, kb = fi & 7;                                   \
          const float4 w = *(const float4*)(E + (size_t)(col0 + rb) * DIM + (k0 + kb * 4)); \
          b_s[kb * 4 + 0][rb] = w.x; b_s[kb * 4 + 1][rb] = w.y;                  \
          b_s[kb * 4 + 2][rb] = w.z; b_s[kb * 4 + 3][rb] = w.w;                  \
        }                                                                        \
      }                                                                          \
      __syncthreads();                                                           \
      _Pragma("unroll")                                                          \
      for (int k = 0; k < BK; k++) {                                             \
        const float2 a2 = *(const float2*)&a_s[k][ty * 2];                       \
        float br[8];                                                             \
        *(float4*)(br)     = *(const float4*)&b_s[k][tx * 8];                    \
        *(float4*)(br + 4) = *(const float4*)&b_s[k][tx * 8 + 4];                \
        _Pragma("unroll")                                                        \
        for (int j = 0; j < 8; j++) {                                            \
          ACC[0][j] = fmaf(a2.x, br[j], ACC[0][j]);                              \
          ACC[1][j] = fmaf(a2.y, br[j], ACC[1][j]);                              \
        }                                                                        \
      }                                                                          \
    }

  for (int ct = 0; ct < NTOK / BN; ++ct) {
    const int col0 = ct * BN;

    float accA[2][8], accB[2][8];
#pragma unroll
    for (int i = 0; i < 2; i++)
#pragma unroll
      for (int j = 0; j < 8; j++) { accA[i][j] = 0.f; accB[i][j] = 0.f; }

    for (int k0 = 0; k0 < KSPLIT; k0 += BK) GEMM_STEP(k0, accA)
    for (int k0 = KSPLIT; k0 < DIM; k0 += BK) GEMM_STEP(k0, accB)

    float e2v[8];
    *(float4*)(e2v)     = *(const float4*)(e2 + col0 + tx * 8);
    *(float4*)(e2v + 4) = *(const float4*)(e2 + col0 + tx * 8 + 4);
#pragma unroll
    for (int i = 0; i < 2; i++) {
#pragma unroll
      for (int j = 0; j < 8; j++) {
        const float dot = accA[i][j] + accB[i][j];
        const float se = x2r[i] + e2v[j];
        const float d = fmaf(-2.0f, dot, se);
        const int ci = col0 + tx * 8 + j;
        ins4(bv[i], bi[i], d, ci);
      }
    }
  }
#undef GEMM_STEP

#pragma unroll
  for (int m = 1; m < 16; m <<= 1) {
#pragma unroll
    for (int i = 0; i < 2; i++) {
      float ov[4]; int oi[4];
#pragma unroll
      for (int c = 0; c < 4; c++) {
        ov[c] = __shfl_xor(bv[i][c], m, 64);
        oi[c] = __shfl_xor(bi[i][c], m, 64);
      }
#pragma unroll
      for (int c = 0; c < 4; c++) ins4(bv[i], bi[i], ov[c], oi[c]);
    }
  }

#pragma unroll
  for (int i = 0; i < 2; i++) {
    if (tx == i) {
      const int gr = row0 + ty * 2 + i;
      out[EI_OFF + gr] = (float)bi[i][0];
      const double d1 = (double)bv[i][1], d2 = (double)bv[i][2], d3 = (double)bv[i][3];
      double nrm = sqrt(d1 * d1 + d2 * d2 + d3 * d3);
      nrm = fmax(nrm, 1e-12);
      const double t1 = 1.0 / (d1 / nrm + 1e-4);
      const double t2 = 1.0 / (d2 / nrm + 1e-4);
      const double t3 = 1.0 / (d3 / nrm + 1e-4);
      const double mx = fmax(t1, fmax(t2, t3));
      const double e1 = exp(t1 - mx), e2x = exp(t2 - mx), e3 = exp(t3 - mx);
      const double s = e1 + e2x + e3;
      out[TV_OFF + gr * 3 + 0] = (float)(e1 / s);
      out[TV_OFF + gr * 3 + 1] = (float)(e2x / s);
      out[TV_OFF + gr * 3 + 2] = (float)(e3 / s);
      out[TI_OFF + gr * 3 + 0] = (float)bi[i][1];
      out[TI_OFF + gr * 3 + 1] = (float)bi[i][2];
      out[TI_OFF + gr * 3 + 2] = (float)bi[i][3];
    }
  }

  __syncthreads();
  int* idx_sh = (int*)&a_s[0][0];
  if (tx == 0) idx_sh[ty * 2 + 0] = bi[0][0];
  if (tx == 1) idx_sh[ty * 2 + 1] = bi[1][0];
  __syncthreads();

  for (int f = tid; f < BM * (DIM / 4); f += NT) {
    const int r = f / (DIM / 4);
    const int c = f % (DIM / 4);
    const int e = idx_sh[r];
    const float4 v = *(const float4*)(E + (size_t)e * DIM + c * 4);
    *(float4*)(out + Q_OFF + (size_t)(row0 + r) * DIM + c * 4) = v;
  }
}

// ---------------------------------------------------------------- launch
extern "C" void kernel_launch(void* const* d_in, const int* in_sizes, int n_in,
                              void* d_out, int out_size, void* d_ws, size_t ws_size,
                              hipStream_t stream) {
  const float* x = (const float*)d_in[0];  // inputs_flatten [32768,768]
  const float* E = (const float*)d_in[1];  // embed          [8192,768]
  float* out = (float*)d_out;

  // ws layout (bytes)
  unsigned char* ws = (unsigned char*)d_ws;
  float* e2 = (float*)ws;                                   // 8192 f32
  float* x2 = (float*)(ws + 32768);                         // 32768 f32
  int* topi = (int*)(ws + 32768 + 131072);                  // 32768*8 int
  unsigned short* xb = (unsigned short*)(ws + 32768 + 131072 + 1048576);
  unsigned short* eb = xb + (size_t)NROWS * DIM;
  const size_t need = 32768 + 131072 + 1048576 +
                      (size_t)NROWS * DIM * 2 + (size_t)NTOK * DIM * 2;  // ~61.2 MiB

  np_norm_kernel<<<NTOK / 4, 256, 0, stream>>>(E, e2);
  np_norm_kernel<<<NROWS / 4, 256, 0, stream>>>(x, x2);

  if (ws_size >= need) {
    cvt_bf16_kernel<<<2048, 256, 0, stream>>>(x, xb, NROWS * DIM / 4);
    cvt_bf16_kernel<<<512, 256, 0, stream>>>(E, eb, NTOK * DIM / 4);
    vq_rank<<<NROWS / 128, 512, 0, stream>>>(xb, eb, e2, topi);
    vq_refine<<<NROWS * 8 / 256, 256, 0, stream>>>(x, E, x2, e2, topi, out);
  } else {
    vq_main<<<NROWS / BM, NT, 0, stream>>>(x, E, x2, e2, out);
  }
}

// Round 6
// 1179.363 us; speedup vs baseline: 7.3570x; 1.6093x over previous
//
#include <hip/hip_runtime.h>
#include <cfloat>
#include <cmath>

#define NROWS 32768
#define NTOK  8192
#define DIM   768
#define KSPLIT 384   // OpenBLAS sgemm kc — K=768 -> two sequential fp32 chains (verified R4)

// fallback (R4) tiling
#define BM 64
#define BN 128
#define BK 32
#define NT 512

// float offsets in d_out (concatenated outputs, all read back as f32)
#define Q_OFF   0
#define EI_OFF  (NROWS*DIM)          // 25165824
#define TV_OFF  (EI_OFF + NROWS)     // 25198592
#define TI_OFF  (TV_OFF + NROWS*3)   // 25296896

typedef short short8 __attribute__((ext_vector_type(8)));
typedef float f32x4 __attribute__((ext_vector_type(4)));
typedef float f32x16 __attribute__((ext_vector_type(16)));

// ---------------------------------------------------------------- numpy-exact row sum of squares
// (verified bit-exact in R4 — do not touch)
__global__ __launch_bounds__(256)
void np_norm_kernel(const float* __restrict__ x, float* __restrict__ o) {
#pragma clang fp contract(off)
  const int wid = (blockIdx.x * 256 + threadIdx.x) >> 6;  // one wave per row
  const int lane = threadIdx.x & 63;
  const float* p = x + (size_t)wid * DIM + (lane >> 3) * 96 + (lane & 7);
  float v = p[0];
  float r = v * v;
#pragma unroll
  for (int k = 1; k < 12; k++) {
    float w = p[8 * k];
    float sq = w * w;
    r = r + sq;
  }
#pragma unroll
  for (int m = 1; m < 64; m <<= 1) {
    float other = __shfl_xor(r, m, 64);
    r = r + other;
  }
  if (lane == 0) o[wid] = r;
}

// ---------------------------------------------------------------- helpers
__device__ __forceinline__ bool dless(float a, int ai, float b, int bi_) {
  return (a < b) || (a == b && ai < bi_);
}

__device__ __forceinline__ void ins4(float (&v)[4], int (&x)[4], float c, int ci) {
  if (dless(c, ci, v[3], x[3])) {
    v[3] = c; x[3] = ci;
    if (dless(v[3], x[3], v[2], x[2])) { float tv = v[2]; int ti = x[2]; v[2] = v[3]; x[2] = x[3]; v[3] = tv; x[3] = ti; }
    if (dless(v[2], x[2], v[1], x[1])) { float tv = v[1]; int ti = x[1]; v[1] = v[2]; x[1] = x[2]; v[2] = tv; x[2] = ti; }
    if (dless(v[1], x[1], v[0], x[0])) { float tv = v[0]; int ti = x[0]; v[0] = v[1]; x[0] = x[1]; v[1] = tv; x[1] = ti; }
  }
}

__device__ __forceinline__ void ins8(float (&v)[8], int (&x)[8], float c, int ci) {
  if (dless(c, ci, v[7], x[7])) {
    v[7] = c; x[7] = ci;
#pragma unroll
    for (int k = 7; k > 0; k--) {
      if (dless(v[k], x[k], v[k - 1], x[k - 1])) {
        float tv = v[k - 1]; int ti = x[k - 1];
        v[k - 1] = v[k]; x[k - 1] = x[k];
        v[k] = tv; x[k] = ti;
      }
    }
  }
}

__device__ __forceinline__ unsigned short f2bf(float f) {  // RNE fp32 -> bf16
  unsigned int u = __float_as_uint(f);
  u += 0x7FFFu + ((u >> 16) & 1u);
  return (unsigned short)(u >> 16);
}

typedef const __attribute__((address_space(1))) void* gas1_t;
typedef __attribute__((address_space(3))) void* las3_t;
__device__ __forceinline__ void gl16(const void* g, void* s) {
  // async global->LDS, 16B per lane; LDS dest = wave-uniform base + lane*16
  __builtin_amdgcn_global_load_lds((gas1_t)g, (las3_t)s, 16, 0, 0);
}

// ---------------------------------------------------------------- bf16 transposed pre-convert
// out layout: 16B chunk (Q, row) at out + (Q*nrows + row)*8 ushorts, Q = k-octet (0..95)
__global__ __launch_bounds__(256)
void cvtT_kernel(const float* __restrict__ in, unsigned short* __restrict__ out, int nrows) {
  const int row = blockIdx.x * 256 + threadIdx.x;
  const int Q = blockIdx.y;
  const float4* p = (const float4*)(in + (size_t)row * DIM + Q * 8);
  const float4 a = p[0], b = p[1];
  union { unsigned short u[8]; int4 v; } pk;
  pk.u[0] = f2bf(a.x); pk.u[1] = f2bf(a.y); pk.u[2] = f2bf(a.z); pk.u[3] = f2bf(a.w);
  pk.u[4] = f2bf(b.x); pk.u[5] = f2bf(b.y); pk.u[6] = f2bf(b.z); pk.u[7] = f2bf(b.w);
  *(int4*)(out + ((size_t)Q * nrows + row) * 8) = pk.v;
}

// ---------------------------------------------------------------- stage 1: swapped-operand MFMA rank
// block: 512 thr (8 waves: wr 0..3 x wc 0..1), 256 rows x 4096 cols (col-half grid),
// strips of 256 cols, K-chunk 32, mfma 32x32x16 bf16 with A=E, B=X so each lane
// owns ONE x-row per acc (col=lane&31) -> selection fully in registers.
#define STRIPS 16
#define KSTEPS 24
#define NITER (STRIPS * KSTEPS)

__global__ __launch_bounds__(512, 2)
void vq_rank(const unsigned short* __restrict__ xbT, const unsigned short* __restrict__ ebT,
             const float* __restrict__ e2g, unsigned short* __restrict__ topp) {
  __shared__ __align__(16) unsigned char xsm[2][16384];  // [kq 0..3][row 0..255] 16B chunks
  __shared__ __align__(16) unsigned char esm[2][16384];  // [kq 0..3][col 0..255]
  __shared__ __align__(16) float e2s[4096];

  const int tid = threadIdx.x;
  const int l = tid & 63;
  const int w = tid >> 6;
  const int wr = w >> 1, wc = w & 1;
  const int l31 = l & 31, h = l >> 5;

  // bijective XCD swizzle (256 blocks % 8 == 0)
  const int bid = (int)blockIdx.x;
  const int sbid = (bid & 7) * 32 + (bid >> 3);
  const int rb = sbid >> 1;
  const int chalf = sbid & 1;
  const int row0 = rb * 256;
  const int cg0 = chalf * 4096;

  // staging lane roles (constant)
  const int st_kq = w >> 2;            // + c*2
  const int st_idx = (w & 3) * 64 + l; // row or col within 256

  float bv[2][8]; int bi[2][8];
#pragma unroll
  for (int xj = 0; xj < 2; ++xj)
#pragma unroll
    for (int c = 0; c < 8; ++c) { bv[xj][c] = FLT_MAX; bi[xj][c] = 0x7FFFFFFF; }

  f32x16 acc[4][2];
#pragma unroll
  for (int ei = 0; ei < 4; ++ei)
#pragma unroll
    for (int xj = 0; xj < 2; ++xj) acc[ei][xj] = (f32x16)0.f;

#define STAGE(buf, k0n, cg)                                                     \
  {                                                                             \
    const int Qb = (k0n) >> 3;                                                  \
    _Pragma("unroll")                                                           \
    for (int c = 0; c < 2; ++c) {                                               \
      gl16(xbT + ((size_t)(Qb + c * 2 + st_kq) * NROWS + row0 + st_idx) * 8,    \
           &xsm[buf][(c * 512 + w * 64) * 16]);                                 \
    }                                                                           \
    _Pragma("unroll")                                                           \
    for (int c = 0; c < 2; ++c) {                                               \
      gl16(ebT + ((size_t)(Qb + c * 2 + st_kq) * NTOK + (cg) + st_idx) * 8,     \
           &esm[buf][(c * 512 + w * 64) * 16]);                                 \
    }                                                                           \
  }

  // prologue: e2 strip (16KB) + first tile
#pragma unroll
  for (int c = 0; c < 2; ++c) {
    const int f = c * 512 + w * 64;
    gl16((const unsigned char*)e2g + (size_t)(cg0) * 4 + (size_t)(f + l) * 16,
         (unsigned char*)e2s + f * 16);
  }
  STAGE(0, 0, cg0)
  __syncthreads();

  int cur = 0;
  for (int t = 0; t < NITER; ++t) {
    const int st = t / KSTEPS;
    const int kk = t - st * KSTEPS;
    if (t + 1 < NITER) {
      const int st2 = (t + 1) / KSTEPS;
      const int kk2 = (t + 1) - st2 * KSTEPS;
      STAGE(cur ^ 1, kk2 * 32, cg0 + st2 * 256)
    }
    // compute current tile
    const unsigned char* xb = xsm[cur];
    const unsigned char* ebp = esm[cur];
#pragma unroll
    for (int s = 0; s < 2; ++s) {
      const int kqo = (s * 2 + h) * 256;
      short8 af[4], bfr[2];
#pragma unroll
      for (int ei = 0; ei < 4; ++ei)
        af[ei] = *(const short8*)(ebp + (size_t)(kqo + wc * 128 + ei * 32 + l31) * 16);
#pragma unroll
      for (int xj = 0; xj < 2; ++xj)
        bfr[xj] = *(const short8*)(xb + (size_t)(kqo + wr * 64 + xj * 32 + l31) * 16);
#pragma unroll
      for (int ei = 0; ei < 4; ++ei)
#pragma unroll
        for (int xj = 0; xj < 2; ++xj)
          acc[ei][xj] = __builtin_amdgcn_mfma_f32_32x32x16_bf16(af[ei], bfr[xj], acc[ei][xj], 0, 0, 0);
    }

    if (kk == KSTEPS - 1) {
      // selection: s = e2[col] - 2*dot (x2 row-constant: rank-invariant)
      const int sb = st * 256 + wc * 128;
#pragma unroll
      for (int ei = 0; ei < 4; ++ei) {
        float4 e2q[4];
#pragma unroll
        for (int q = 0; q < 4; ++q)
          e2q[q] = *(const float4*)&e2s[sb + ei * 32 + q * 8 + 4 * h];
        const int cb = cg0 + sb + ei * 32 + 4 * h;
#pragma unroll
        for (int xj = 0; xj < 2; ++xj) {
          float sv[16];
#pragma unroll
          for (int q = 0; q < 4; ++q) {
            sv[q * 4 + 0] = fmaf(-2.f, acc[ei][xj][q * 4 + 0], e2q[q].x);
            sv[q * 4 + 1] = fmaf(-2.f, acc[ei][xj][q * 4 + 1], e2q[q].y);
            sv[q * 4 + 2] = fmaf(-2.f, acc[ei][xj][q * 4 + 2], e2q[q].z);
            sv[q * 4 + 3] = fmaf(-2.f, acc[ei][xj][q * 4 + 3], e2q[q].w);
          }
          float mn = sv[0];
#pragma unroll
          for (int r = 1; r < 16; ++r) mn = fminf(mn, sv[r]);
          if (mn < bv[xj][7]) {
#pragma unroll
            for (int q = 0; q < 4; ++q)
#pragma unroll
              for (int j = 0; j < 4; ++j)
                ins8(bv[xj], bi[xj], sv[q * 4 + j], cb + q * 8 + j);
          }
        }
      }
#pragma unroll
      for (int ei = 0; ei < 4; ++ei)
#pragma unroll
        for (int xj = 0; xj < 2; ++xj) acc[ei][xj] = (f32x16)0.f;
    }
    __syncthreads();
    cur ^= 1;
  }
#undef STAGE

  // h-merge (lanes l and l+32 hold same x-row)
#pragma unroll
  for (int xj = 0; xj < 2; ++xj) {
    float ov[8]; int oi[8];
#pragma unroll
    for (int c = 0; c < 8; ++c) {
      ov[c] = __shfl_xor(bv[xj][c], 32, 64);
      oi[c] = __shfl_xor(bi[xj][c], 32, 64);
    }
#pragma unroll
    for (int c = 0; c < 8; ++c) ins8(bv[xj], bi[xj], ov[c], oi[c]);
  }

  // cross-wc merge via LDS (dbuf is dead)
  __syncthreads();
  float* mval = (float*)&xsm[0][0];
  int* midx = (int*)&esm[0][0];
  if (l < 32) {
#pragma unroll
    for (int xj = 0; xj < 2; ++xj) {
      const int rr = wr * 64 + xj * 32 + l31;
#pragma unroll
      for (int c = 0; c < 8; ++c) {
        mval[(wc * 256 + rr) * 8 + c] = bv[xj][c];
        midx[(wc * 256 + rr) * 8 + c] = bi[xj][c];
      }
    }
  }
  __syncthreads();
  if (wc == 0 && l < 32) {
#pragma unroll
    for (int xj = 0; xj < 2; ++xj) {
      const int rr = wr * 64 + xj * 32 + l31;
      const float* ov = &mval[(256 + rr) * 8];
      const int* oi = &midx[(256 + rr) * 8];
#pragma unroll
      for (int c = 0; c < 8; ++c) ins8(bv[xj], bi[xj], ov[c], oi[c]);
      unsigned short* dst = topp + (size_t)(row0 + rr) * 16 + chalf * 8;
#pragma unroll
      for (int c = 0; c < 8; ++c) dst[c] = (unsigned short)bi[xj][c];
    }
  }
}

// ---------------------------------------------------------------- stage 2: exact fp32 refine of 16 candidates
__global__ __launch_bounds__(256)
void vq_refine16(const float* __restrict__ x, const float* __restrict__ E,
                 const float* __restrict__ x2, const float* __restrict__ e2,
                 const unsigned short* __restrict__ topp, float* __restrict__ out) {
  const int gid = blockIdx.x * 256 + threadIdx.x;
  const int row = gid >> 4;
  const int s = gid & 15;
  const int myc = topp[(size_t)row * 16 + s];

  const float4* xr = (const float4*)(x + (size_t)row * DIM);
  const float4* er = (const float4*)(E + (size_t)myc * DIM);
  // two sequential fp32 fma chains split at KSPLIT (identical to R4's verified arithmetic)
  float accA = 0.f, accB = 0.f;
#pragma unroll 8
  for (int q = 0; q < KSPLIT / 4; ++q) {
    const float4 a = xr[q], b = er[q];
    accA = fmaf(a.x, b.x, accA); accA = fmaf(a.y, b.y, accA);
    accA = fmaf(a.z, b.z, accA); accA = fmaf(a.w, b.w, accA);
  }
#pragma unroll 8
  for (int q = KSPLIT / 4; q < DIM / 4; ++q) {
    const float4 a = xr[q], b = er[q];
    accB = fmaf(a.x, b.x, accB); accB = fmaf(a.y, b.y, accB);
    accB = fmaf(a.z, b.z, accB); accB = fmaf(a.w, b.w, accB);
  }
  const float d = fmaf(-2.0f, accA + accB, x2[row] + e2[myc]);

  // gather all 16 candidates of this row within the 16-lane group
  const int base = (threadIdx.x & 63) & ~15;
  float dv[16]; int cv[16];
#pragma unroll
  for (int t = 0; t < 16; ++t) {
    dv[t] = __shfl(d, base + t, 64);
    cv[t] = __shfl(myc, base + t, 64);
  }
  // 4 bubble passes -> slots 0..3 are the exact ascending top-4 (static indices only)
#pragma unroll
  for (int a = 0; a < 4; ++a)
#pragma unroll
    for (int b = 15; b > a; --b) {
      const bool sw = (dv[b] < dv[b - 1]) || (dv[b] == dv[b - 1] && cv[b] < cv[b - 1]);
      if (sw) {
        float td = dv[b]; dv[b] = dv[b - 1]; dv[b - 1] = td;
        int ti = cv[b]; cv[b] = cv[b - 1]; cv[b - 1] = ti;
      }
    }

  if (s == 0) {
    out[EI_OFF + row] = (float)cv[0];
    const double d1 = (double)dv[1], d2 = (double)dv[2], d3 = (double)dv[3];
    double nrm = sqrt(d1 * d1 + d2 * d2 + d3 * d3);
    nrm = fmax(nrm, 1e-12);
    const double t1 = 1.0 / (d1 / nrm + 1e-4);
    const double t2 = 1.0 / (d2 / nrm + 1e-4);
    const double t3 = 1.0 / (d3 / nrm + 1e-4);
    const double mx = fmax(t1, fmax(t2, t3));
    const double e1 = exp(t1 - mx), e2x = exp(t2 - mx), e3 = exp(t3 - mx);
    const double sm = e1 + e2x + e3;
    out[TV_OFF + row * 3 + 0] = (float)(e1 / sm);
    out[TV_OFF + row * 3 + 1] = (float)(e2x / sm);
    out[TV_OFF + row * 3 + 2] = (float)(e3 / sm);
    out[TI_OFF + row * 3 + 0] = (float)cv[1];
    out[TI_OFF + row * 3 + 1] = (float)cv[2];
    out[TI_OFF + row * 3 + 2] = (float)cv[3];
  }

  // quantize = embed[argmin]: 16-lane cooperative float4 copy (192 float4 per row)
  const float4* src = (const float4*)(E + (size_t)cv[0] * DIM);
  float4* dst = (float4*)(out + Q_OFF + (size_t)row * DIM);
#pragma unroll
  for (int k = 0; k < 12; ++k) dst[s + k * 16] = src[s + k * 16];
}

// ---------------------------------------------------------------- fallback: R4's passing fused fp32 kernel
__global__ __launch_bounds__(NT, 4)
void vq_main(const float* __restrict__ A, const float* __restrict__ E,
             const float* __restrict__ x2, const float* __restrict__ e2,
             float* __restrict__ out) {
  __shared__ float a_s[BK][BM + 4];
  __shared__ float b_s[BK][BN + 4];

  const int tid = threadIdx.x;
  const int tx = tid & 15;
  const int ty = tid >> 4;
  const int row0 = blockIdx.x * BM;

  const float x2r[2] = { x2[row0 + ty * 2 + 0], x2[row0 + ty * 2 + 1] };

  float bv[2][4];
  int   bi[2][4];
#pragma unroll
  for (int i = 0; i < 2; i++)
#pragma unroll
    for (int c = 0; c < 4; c++) { bv[i][c] = FLT_MAX; bi[i][c] = 0x7FFFFFFF; }

#define GEMM_STEP(k0, ACC)                                                       \
    {                                                                            \
      __syncthreads();                                                           \
      {                                                                          \
        const int r = tid >> 3, kq = tid & 7;                                    \
        const float4 v = *(const float4*)(A + (size_t)(row0 + r) * DIM + (k0 + kq * 4)); \
        a_s[kq * 4 + 0][r] = v.x; a_s[kq * 4 + 1][r] = v.y;                      \
        a_s[kq * 4 + 2][r] = v.z; a_s[kq * 4 + 3][r] = v.w;                      \
        _Pragma("unroll")                                                        \
        for (int s = 0; s < 2; s++) {                                            \
          const int fi = tid + s * NT;                                           \
          const int rb = fi >> 3, kb = fi & 7;                                   \
          const float4 w = *(const float4*)(E + (size_t)(col0 + rb) * DIM + (k0 + kb * 4)); \
          b_s[kb * 4 + 0][rb] = w.x; b_s[kb * 4 + 1][rb] = w.y;                  \
          b_s[kb * 4 + 2][rb] = w.z; b_s[kb * 4 + 3][rb] = w.w;                  \
        }                                                                        \
      }                                                                          \
      __syncthreads();                                                           \
      _Pragma("unroll")                                                          \
      for (int k = 0; k < BK; k++) {                                             \
        const float2 a2 = *(const float2*)&a_s[k][ty * 2];                       \
        float br[8];                                                             \
        *(float4*)(br)     = *(const float4*)&b_s[k][tx * 8];                    \
        *(float4*)(br + 4) = *(const float4*)&b_s[k][tx * 8 + 4];                \
        _Pragma("unroll")                                                        \
        for (int j = 0; j < 8; j++) {                                            \
          ACC[0][j] = fmaf(a2.x, br[j], ACC[0][j]);                              \
          ACC[1][j] = fmaf(a2.y, br[j], ACC[1][j]);                              \
        }                                                                        \
      }                                                                          \
    }

  for (int ct = 0; ct < NTOK / BN; ++ct) {
    const int col0 = ct * BN;

    float accA[2][8], accB[2][8];
#pragma unroll
    for (int i = 0; i < 2; i++)
#pragma unroll
      for (int j = 0; j < 8; j++) { accA[i][j] = 0.f; accB[i][j] = 0.f; }

    for (int k0 = 0; k0 < KSPLIT; k0 += BK) GEMM_STEP(k0, accA)
    for (int k0 = KSPLIT; k0 < DIM; k0 += BK) GEMM_STEP(k0, accB)

    float e2v[8];
    *(float4*)(e2v)     = *(const float4*)(e2 + col0 + tx * 8);
    *(float4*)(e2v + 4) = *(const float4*)(e2 + col0 + tx * 8 + 4);
#pragma unroll
    for (int i = 0; i < 2; i++) {
#pragma unroll
      for (int j = 0; j < 8; j++) {
        const float dot = accA[i][j] + accB[i][j];
        const float se = x2r[i] + e2v[j];
        const float d = fmaf(-2.0f, dot, se);
        const int ci = col0 + tx * 8 + j;
        ins4(bv[i], bi[i], d, ci);
      }
    }
  }
#undef GEMM_STEP

#pragma unroll
  for (int m = 1; m < 16; m <<= 1) {
#pragma unroll
    for (int i = 0; i < 2; i++) {
      float ov[4]; int oi[4];
#pragma unroll
      for (int c = 0; c < 4; c++) {
        ov[c] = __shfl_xor(bv[i][c], m, 64);
        oi[c] = __shfl_xor(bi[i][c], m, 64);
      }
#pragma unroll
      for (int c = 0; c < 4; c++) ins4(bv[i], bi[i], ov[c], oi[c]);
    }
  }

#pragma unroll
  for (int i = 0; i < 2; i++) {
    if (tx == i) {
      const int gr = row0 + ty * 2 + i;
      out[EI_OFF + gr] = (float)bi[i][0];
      const double d1 = (double)bv[i][1], d2 = (double)bv[i][2], d3 = (double)bv[i][3];
      double nrm = sqrt(d1 * d1 + d2 * d2 + d3 * d3);
      nrm = fmax(nrm, 1e-12);
      const double t1 = 1.0 / (d1 / nrm + 1e-4);
      const double t2 = 1.0 / (d2 / nrm + 1e-4);
      const double t3 = 1.0 / (d3 / nrm + 1e-4);
      const double mx = fmax(t1, fmax(t2, t3));
      const double e1 = exp(t1 - mx), e2x = exp(t2 - mx), e3 = exp(t3 - mx);
      const double s = e1 + e2x + e3;
      out[TV_OFF + gr * 3 + 0] = (float)(e1 / s);
      out[TV_OFF + gr * 3 + 1] = (float)(e2x / s);
      out[TV_OFF + gr * 3 + 2] = (float)(e3 / s);
      out[TI_OFF + gr * 3 + 0] = (float)bi[i][1];
      out[TI_OFF + gr * 3 + 1] = (float)bi[i][2];
      out[TI_OFF + gr * 3 + 2] = (float)bi[i][3];
    }
  }

  __syncthreads();
  int* idx_sh = (int*)&a_s[0][0];
  if (tx == 0) idx_sh[ty * 2 + 0] = bi[0][0];
  if (tx == 1) idx_sh[ty * 2 + 1] = bi[1][0];
  __syncthreads();

  for (int f = tid; f < BM * (DIM / 4); f += NT) {
    const int r = f / (DIM / 4);
    const int c = f % (DIM / 4);
    const int e = idx_sh[r];
    const float4 v = *(const float4*)(E + (size_t)e * DIM + c * 4);
    *(float4*)(out + Q_OFF + (size_t)(row0 + r) * DIM + c * 4) = v;
  }
}

// ---------------------------------------------------------------- launch
extern "C" void kernel_launch(void* const* d_in, const int* in_sizes, int n_in,
                              void* d_out, int out_size, void* d_ws, size_t ws_size,
                              hipStream_t stream) {
  const float* x = (const float*)d_in[0];  // inputs_flatten [32768,768]
  const float* E = (const float*)d_in[1];  // embed          [8192,768]
  float* out = (float*)d_out;

  // ws layout (bytes) — identical footprint to R5 (proven to fit)
  unsigned char* ws = (unsigned char*)d_ws;
  float* e2 = (float*)ws;                                   // 8192 f32
  float* x2 = (float*)(ws + 32768);                         // 32768 f32
  unsigned short* topp = (unsigned short*)(ws + 32768 + 131072);  // 32768*16 u16 = 1MB
  unsigned short* xbT = (unsigned short*)(ws + 32768 + 131072 + 1048576);
  unsigned short* ebT = xbT + (size_t)NROWS * DIM;
  const size_t need = 32768 + 131072 + 1048576 +
                      (size_t)NROWS * DIM * 2 + (size_t)NTOK * DIM * 2;

  np_norm_kernel<<<NTOK / 4, 256, 0, stream>>>(E, e2);
  np_norm_kernel<<<NROWS / 4, 256, 0, stream>>>(x, x2);

  if (ws_size >= need) {
    cvtT_kernel<<<dim3(NROWS / 256, DIM / 8), 256, 0, stream>>>(x, xbT, NROWS);
    cvtT_kernel<<<dim3(NTOK / 256, DIM / 8), 256, 0, stream>>>(E, ebT, NTOK);
    vq_rank<<<256, 512, 0, stream>>>(xbT, ebT, e2, topp);
    vq_refine16<<<NROWS * 16 / 256, 256, 0, stream>>>(x, E, x2, e2, topp, out);
  } else {
    vq_main<<<NROWS / BM, NT, 0, stream>>>(x, E, x2, e2, out);
  }
}

// Round 7
// 1101.206 us; speedup vs baseline: 7.8792x; 1.0710x over previous
//
#include <hip/hip_runtime.h>
#include <cfloat>
#include <cmath>

#define NROWS 32768
#define NTOK  8192
#define DIM   768
#define KSPLIT 384   // OpenBLAS sgemm kc — K=768 -> two sequential fp32 chains (verified R4)

// fallback (R4) tiling
#define BM 64
#define BN 128
#define BK 32
#define NT 512

// float offsets in d_out (concatenated outputs, all read back as f32)
#define Q_OFF   0
#define EI_OFF  (NROWS*DIM)          // 25165824
#define TV_OFF  (EI_OFF + NROWS)     // 25198592
#define TI_OFF  (TV_OFF + NROWS*3)   // 25296896

typedef short short8 __attribute__((ext_vector_type(8)));
typedef float f32x4 __attribute__((ext_vector_type(4)));
typedef float f32x16 __attribute__((ext_vector_type(16)));

// ---------------------------------------------------------------- numpy-exact row sum of squares
// (verified bit-exact in R4 — do not touch)
__global__ __launch_bounds__(256)
void np_norm_kernel(const float* __restrict__ x, float* __restrict__ o) {
#pragma clang fp contract(off)
  const int wid = (blockIdx.x * 256 + threadIdx.x) >> 6;  // one wave per row
  const int lane = threadIdx.x & 63;
  const float* p = x + (size_t)wid * DIM + (lane >> 3) * 96 + (lane & 7);
  float v = p[0];
  float r = v * v;
#pragma unroll
  for (int k = 1; k < 12; k++) {
    float w = p[8 * k];
    float sq = w * w;
    r = r + sq;
  }
#pragma unroll
  for (int m = 1; m < 64; m <<= 1) {
    float other = __shfl_xor(r, m, 64);
    r = r + other;
  }
  if (lane == 0) o[wid] = r;
}

// ---------------------------------------------------------------- helpers
__device__ __forceinline__ bool dless(float a, int ai, float b, int bi_) {
  return (a < b) || (a == b && ai < bi_);
}

__device__ __forceinline__ void ins4(float (&v)[4], int (&x)[4], float c, int ci) {
  if (dless(c, ci, v[3], x[3])) {
    v[3] = c; x[3] = ci;
    if (dless(v[3], x[3], v[2], x[2])) { float tv = v[2]; int ti = x[2]; v[2] = v[3]; x[2] = x[3]; v[3] = tv; x[3] = ti; }
    if (dless(v[2], x[2], v[1], x[1])) { float tv = v[1]; int ti = x[1]; v[1] = v[2]; x[1] = x[2]; v[2] = tv; x[2] = ti; }
    if (dless(v[1], x[1], v[0], x[0])) { float tv = v[0]; int ti = x[0]; v[0] = v[1]; x[0] = x[1]; v[1] = tv; x[1] = ti; }
  }
}

__device__ __forceinline__ void ins8(float (&v)[8], int (&x)[8], float c, int ci) {
  if (dless(c, ci, v[7], x[7])) {
    v[7] = c; x[7] = ci;
#pragma unroll
    for (int k = 7; k > 0; k--) {
      if (dless(v[k], x[k], v[k - 1], x[k - 1])) {
        float tv = v[k - 1]; int ti = x[k - 1];
        v[k - 1] = v[k]; x[k - 1] = x[k];
        v[k] = tv; x[k] = ti;
      }
    }
  }
}

__device__ __forceinline__ unsigned short f2bf(float f) {  // RNE fp32 -> bf16
  unsigned int u = __float_as_uint(f);
  u += 0x7FFFu + ((u >> 16) & 1u);
  return (unsigned short)(u >> 16);
}

typedef const __attribute__((address_space(1))) void* gas1_t;
typedef __attribute__((address_space(3))) void* las3_t;
__device__ __forceinline__ void gl16(const void* g, void* s) {
  // async global->LDS, 16B per lane; LDS dest = wave-uniform base + lane*16
  __builtin_amdgcn_global_load_lds((gas1_t)g, (las3_t)s, 16, 0, 0);
}

// ---------------------------------------------------------------- bf16 transposed pre-convert
// out layout: 16B chunk (Q, row) at out + (Q*nrows + row)*8 ushorts, Q = k-octet (0..95)
__global__ __launch_bounds__(256)
void cvtT_kernel(const float* __restrict__ in, unsigned short* __restrict__ out, int nrows) {
  const int row = blockIdx.x * 256 + threadIdx.x;
  const int Q = blockIdx.y;
  const float4* p = (const float4*)(in + (size_t)row * DIM + Q * 8);
  const float4 a = p[0], b = p[1];
  union { unsigned short u[8]; int4 v; } pk;
  pk.u[0] = f2bf(a.x); pk.u[1] = f2bf(a.y); pk.u[2] = f2bf(a.z); pk.u[3] = f2bf(a.w);
  pk.u[4] = f2bf(b.x); pk.u[5] = f2bf(b.y); pk.u[6] = f2bf(b.z); pk.u[7] = f2bf(b.w);
  *(int4*)(out + ((size_t)Q * nrows + row) * 8) = pk.v;
}

// ---------------------------------------------------------------- stage 1: swapped-operand MFMA rank
// 4-buffer ring, stage 3 tiles ahead, counted vmcnt(8) + raw s_barrier (T3/T4).
#define STRIPS 16
#define KSTEPS 24
#define NITER (STRIPS * KSTEPS)

__global__ __launch_bounds__(512, 2)
void vq_rank(const unsigned short* __restrict__ xbT, const unsigned short* __restrict__ ebT,
             const float* __restrict__ e2g, unsigned short* __restrict__ topp) {
  __shared__ __align__(16) unsigned char xsm[4][16384];  // [buf][kq 0..3][idx 0..255] 16B chunks
  __shared__ __align__(16) unsigned char esm[4][16384];
  __shared__ __align__(16) float e2s[4096];

  const int tid = threadIdx.x;
  const int l = tid & 63;
  const int w = tid >> 6;
  const int wr = w >> 1, wc = w & 1;
  const int l31 = l & 31, h = l >> 5;

  // bijective XCD swizzle (256 blocks % 8 == 0)
  const int bid = (int)blockIdx.x;
  const int sbid = (bid & 7) * 32 + (bid >> 3);
  const int rb = sbid >> 1;
  const int chalf = sbid & 1;
  const int row0 = rb * 256;
  const int cg0 = chalf * 4096;

  // staging lane roles (constant)
  const int st_kq = w >> 2;            // k-octet-pair base
  const int st_idx = (w & 3) * 64 + l; // row or col within 256
  // per-thread staging bases, in ushort units
  const size_t xbase = (size_t)st_kq * NROWS * 8 + ((size_t)(row0 + st_idx)) * 8;
  const size_t ebase = (size_t)st_kq * NTOK * 8 + ((size_t)(cg0 + st_idx)) * 8;

  float bv[2][8]; int bi[2][8];
#pragma unroll
  for (int xj = 0; xj < 2; ++xj)
#pragma unroll
    for (int c = 0; c < 8; ++c) { bv[xj][c] = FLT_MAX; bi[xj][c] = 0x7FFFFFFF; }

  f32x16 acc[4][2];
#pragma unroll
  for (int ei = 0; ei < 4; ++ei)
#pragma unroll
    for (int xj = 0; xj < 2; ++xj) acc[ei][xj] = (f32x16)0.f;

#define STAGE(buf, SKK, SCOFF)                                                  \
  {                                                                             \
    const unsigned short* xs = xbT + xbase + ((size_t)(SKK) << 20);             \
    gl16(xs, &xsm[buf][(w * 64) * 16]);                                         \
    gl16(xs + NROWS * 16, &xsm[buf][(512 + w * 64) * 16]);                      \
    const unsigned short* es = ebT + ebase + ((size_t)(SKK) << 18) +            \
                               ((size_t)(SCOFF) << 3);                          \
    gl16(es, &esm[buf][(w * 64) * 16]);                                         \
    gl16(es + NTOK * 16, &esm[buf][(512 + w * 64) * 16]);                       \
  }

#define COMPUTE(b)                                                              \
  {                                                                             \
    const unsigned char* xb = &xsm[b][0];                                       \
    const unsigned char* ebp = &esm[b][0];                                      \
    _Pragma("unroll")                                                           \
    for (int s = 0; s < 2; ++s) {                                               \
      const int kqo = (s * 2 + h) * 256;                                        \
      short8 af[4], bfr[2];                                                     \
      _Pragma("unroll")                                                         \
      for (int ei = 0; ei < 4; ++ei)                                            \
        af[ei] = *(const short8*)(ebp + (size_t)(kqo + wc * 128 + ei * 32 + l31) * 16); \
      _Pragma("unroll")                                                         \
      for (int xj = 0; xj < 2; ++xj)                                            \
        bfr[xj] = *(const short8*)(xb + (size_t)(kqo + wr * 64 + xj * 32 + l31) * 16); \
      _Pragma("unroll")                                                         \
      for (int ei = 0; ei < 4; ++ei)                                            \
        _Pragma("unroll")                                                       \
        for (int xj = 0; xj < 2; ++xj)                                          \
          acc[ei][xj] = __builtin_amdgcn_mfma_f32_32x32x16_bf16(af[ei], bfr[xj], acc[ei][xj], 0, 0, 0); \
    }                                                                           \
  }

#define SELECT                                                                  \
  {                                                                             \
    _Pragma("unroll")                                                           \
    for (int ei = 0; ei < 4; ++ei) {                                            \
      float4 e2q[4];                                                            \
      _Pragma("unroll")                                                         \
      for (int q = 0; q < 4; ++q)                                               \
        e2q[q] = *(const float4*)&e2s[selb + wc * 128 + ei * 32 + q * 8 + 4 * h]; \
      const int cb = cg0 + selb + wc * 128 + ei * 32 + 4 * h;                   \
      _Pragma("unroll")                                                         \
      for (int xj = 0; xj < 2; ++xj) {                                          \
        float sv[16];                                                           \
        _Pragma("unroll")                                                       \
        for (int q = 0; q < 4; ++q) {                                           \
          sv[q * 4 + 0] = fmaf(-2.f, acc[ei][xj][q * 4 + 0], e2q[q].x);         \
          sv[q * 4 + 1] = fmaf(-2.f, acc[ei][xj][q * 4 + 1], e2q[q].y);         \
          sv[q * 4 + 2] = fmaf(-2.f, acc[ei][xj][q * 4 + 2], e2q[q].z);         \
          sv[q * 4 + 3] = fmaf(-2.f, acc[ei][xj][q * 4 + 3], e2q[q].w);         \
        }                                                                       \
        float mn = sv[0];                                                       \
        _Pragma("unroll")                                                       \
        for (int r = 1; r < 16; ++r) mn = fminf(mn, sv[r]);                     \
        if (mn < bv[xj][7]) {                                                   \
          _Pragma("unroll")                                                     \
          for (int q = 0; q < 4; ++q)                                           \
            _Pragma("unroll")                                                   \
            for (int j = 0; j < 4; ++j)                                         \
              ins8(bv[xj], bi[xj], sv[q * 4 + j], cb + q * 8 + j);              \
        }                                                                       \
      }                                                                         \
    }                                                                           \
    _Pragma("unroll")                                                           \
    for (int ei = 0; ei < 4; ++ei)                                              \
      _Pragma("unroll")                                                         \
      for (int xj = 0; xj < 2; ++xj) acc[ei][xj] = (f32x16)0.f;                 \
  }

#define WAIT8 { asm volatile("s_waitcnt vmcnt(8)" ::: "memory"); __builtin_amdgcn_s_barrier(); asm volatile("" ::: "memory"); }
#define WAIT4 { asm volatile("s_waitcnt vmcnt(4)" ::: "memory"); __builtin_amdgcn_s_barrier(); asm volatile("" ::: "memory"); }
#define WAIT0 { asm volatile("s_waitcnt vmcnt(0)" ::: "memory"); __builtin_amdgcn_s_barrier(); asm volatile("" ::: "memory"); }

  // prologue: e2 strip (16KB) + tiles 0..2
#pragma unroll
  for (int c = 0; c < 2; ++c) {
    const int f = c * 512 + w * 64;
    gl16((const unsigned char*)e2g + (size_t)cg0 * 4 + (size_t)(f + l) * 16,
         (unsigned char*)e2s + f * 16);
  }
  STAGE(0, 0, 0)
  STAGE(1, 1, 0)
  STAGE(2, 2, 0)
  WAIT8  // e2 + tile0 done; tiles 1,2 in flight

  int skk = 3, scoff = 0;  // coords of next tile to stage (t+3)
  int kc = 0, selb = 0;    // current-tile kstep counter / selection col base (within half)

#define BODY_MAIN(b)                                                            \
  {                                                                             \
    STAGE(((b) + 3) & 3, skk, scoff)                                            \
    if (++skk == KSTEPS) { skk = 0; scoff += 256; }                             \
    COMPUTE(b)                                                                  \
    if (++kc == KSTEPS) { SELECT kc = 0; selb += 256; }                         \
    WAIT8                                                                       \
  }

  for (int t = 0; t < NITER - 12; t += 4) {
    BODY_MAIN(0)
    BODY_MAIN(1)
    BODY_MAIN(2)
    BODY_MAIN(3)
  }

  // tail: t = NITER-12 .. NITER-1, fully unrolled (buf indices fold to constants)
#pragma unroll
  for (int tt = 0; tt < 12; ++tt) {
    const int t = NITER - 12 + tt;
    const int b = t & 3;
    if (t + 3 < NITER) {
      STAGE((b + 3) & 3, skk, scoff)
      if (++skk == KSTEPS) { skk = 0; scoff += 256; }
    }
    COMPUTE(b)
    if (++kc == KSTEPS) { SELECT kc = 0; selb += 256; }
    if (t + 3 < NITER) { WAIT8 }
    else if (t + 2 < NITER) { WAIT4 }
    else if (t + 1 < NITER) { WAIT0 }
  }
#undef BODY_MAIN
#undef WAIT8
#undef WAIT4
#undef WAIT0
#undef SELECT
#undef COMPUTE
#undef STAGE

  // h-merge (lanes l and l+32 hold same x-row)
#pragma unroll
  for (int xj = 0; xj < 2; ++xj) {
    float ov[8]; int oi[8];
#pragma unroll
    for (int c = 0; c < 8; ++c) {
      ov[c] = __shfl_xor(bv[xj][c], 32, 64);
      oi[c] = __shfl_xor(bi[xj][c], 32, 64);
    }
#pragma unroll
    for (int c = 0; c < 8; ++c) ins8(bv[xj], bi[xj], ov[c], oi[c]);
  }

  // cross-wc merge via LDS (ring buffers are dead now)
  __syncthreads();
  float* mval = (float*)&xsm[0][0];
  int* midx = (int*)&esm[0][0];
  if (l < 32) {
#pragma unroll
    for (int xj = 0; xj < 2; ++xj) {
      const int rr = wr * 64 + xj * 32 + l31;
#pragma unroll
      for (int c = 0; c < 8; ++c) {
        mval[(wc * 256 + rr) * 8 + c] = bv[xj][c];
        midx[(wc * 256 + rr) * 8 + c] = bi[xj][c];
      }
    }
  }
  __syncthreads();
  if (wc == 0 && l < 32) {
#pragma unroll
    for (int xj = 0; xj < 2; ++xj) {
      const int rr = wr * 64 + xj * 32 + l31;
      const float* ov = &mval[(256 + rr) * 8];
      const int* oi = &midx[(256 + rr) * 8];
#pragma unroll
      for (int c = 0; c < 8; ++c) ins8(bv[xj], bi[xj], ov[c], oi[c]);
      unsigned short* dst = topp + (size_t)(row0 + rr) * 16 + chalf * 8;
#pragma unroll
      for (int c = 0; c < 8; ++c) dst[c] = (unsigned short)bi[xj][c];
    }
  }
}

// ---------------------------------------------------------------- stage 2: exact fp32 refine of 16 candidates
__global__ __launch_bounds__(256)
void vq_refine16(const float* __restrict__ x, const float* __restrict__ E,
                 const float* __restrict__ x2, const float* __restrict__ e2,
                 const unsigned short* __restrict__ topp, float* __restrict__ out) {
  const int gid = blockIdx.x * 256 + threadIdx.x;
  const int row = gid >> 4;
  const int s = gid & 15;
  const int myc = topp[(size_t)row * 16 + s];

  const float4* xr = (const float4*)(x + (size_t)row * DIM);
  const float4* er = (const float4*)(E + (size_t)myc * DIM);
  // two sequential fp32 fma chains split at KSPLIT (identical to R4's verified arithmetic)
  float accA = 0.f, accB = 0.f;
#pragma unroll 8
  for (int q = 0; q < KSPLIT / 4; ++q) {
    const float4 a = xr[q], b = er[q];
    accA = fmaf(a.x, b.x, accA); accA = fmaf(a.y, b.y, accA);
    accA = fmaf(a.z, b.z, accA); accA = fmaf(a.w, b.w, accA);
  }
#pragma unroll 8
  for (int q = KSPLIT / 4; q < DIM / 4; ++q) {
    const float4 a = xr[q], b = er[q];
    accB = fmaf(a.x, b.x, accB); accB = fmaf(a.y, b.y, accB);
    accB = fmaf(a.z, b.z, accB); accB = fmaf(a.w, b.w, accB);
  }
  const float d = fmaf(-2.0f, accA + accB, x2[row] + e2[myc]);

  // gather all 16 candidates of this row within the 16-lane group
  const int base = (threadIdx.x & 63) & ~15;
  float dv[16]; int cv[16];
#pragma unroll
  for (int t = 0; t < 16; ++t) {
    dv[t] = __shfl(d, base + t, 64);
    cv[t] = __shfl(myc, base + t, 64);
  }
  // 4 bubble passes -> slots 0..3 are the exact ascending top-4
#pragma unroll
  for (int a = 0; a < 4; ++a)
#pragma unroll
    for (int b = 15; b > a; --b) {
      const bool sw = (dv[b] < dv[b - 1]) || (dv[b] == dv[b - 1] && cv[b] < cv[b - 1]);
      if (sw) {
        float td = dv[b]; dv[b] = dv[b - 1]; dv[b - 1] = td;
        int ti = cv[b]; cv[b] = cv[b - 1]; cv[b - 1] = ti;
      }
    }

  if (s == 0) {
    out[EI_OFF + row] = (float)cv[0];
    const double d1 = (double)dv[1], d2 = (double)dv[2], d3 = (double)dv[3];
    double nrm = sqrt(d1 * d1 + d2 * d2 + d3 * d3);
    nrm = fmax(nrm, 1e-12);
    const double t1 = 1.0 / (d1 / nrm + 1e-4);
    const double t2 = 1.0 / (d2 / nrm + 1e-4);
    const double t3 = 1.0 / (d3 / nrm + 1e-4);
    const double mx = fmax(t1, fmax(t2, t3));
    const double e1 = exp(t1 - mx), e2x = exp(t2 - mx), e3 = exp(t3 - mx);
    const double sm = e1 + e2x + e3;
    out[TV_OFF + row * 3 + 0] = (float)(e1 / sm);
    out[TV_OFF + row * 3 + 1] = (float)(e2x / sm);
    out[TV_OFF + row * 3 + 2] = (float)(e3 / sm);
    out[TI_OFF + row * 3 + 0] = (float)cv[1];
    out[TI_OFF + row * 3 + 1] = (float)cv[2];
    out[TI_OFF + row * 3 + 2] = (float)cv[3];
  }

  // quantize = embed[argmin]: 16-lane cooperative float4 copy
  const float4* src = (const float4*)(E + (size_t)cv[0] * DIM);
  float4* dst = (float4*)(out + Q_OFF + (size_t)row * DIM);
#pragma unroll
  for (int k = 0; k < 12; ++k) dst[s + k * 16] = src[s + k * 16];
}

// ---------------------------------------------------------------- fallback: R4's passing fused fp32 kernel
__global__ __launch_bounds__(NT, 4)
void vq_main(const float* __restrict__ A, const float* __restrict__ E,
             const float* __restrict__ x2, const float* __restrict__ e2,
             float* __restrict__ out) {
  __shared__ float a_s[BK][BM + 4];
  __shared__ float b_s[BK][BN + 4];

  const int tid = threadIdx.x;
  const int tx = tid & 15;
  const int ty = tid >> 4;
  const int row0 = blockIdx.x * BM;

  const float x2r[2] = { x2[row0 + ty * 2 + 0], x2[row0 + ty * 2 + 1] };

  float bv[2][4];
  int   bi[2][4];
#pragma unroll
  for (int i = 0; i < 2; i++)
#pragma unroll
    for (int c = 0; c < 4; c++) { bv[i][c] = FLT_MAX; bi[i][c] = 0x7FFFFFFF; }

#define GEMM_STEP(k0, ACC)                                                       \
    {                                                                            \
      __syncthreads();                                                           \
      {                                                                          \
        const int r = tid >> 3, kq = tid & 7;                                    \
        const float4 v = *(const float4*)(A + (size_t)(row0 + r) * DIM + (k0 + kq * 4)); \
        a_s[kq * 4 + 0][r] = v.x; a_s[kq * 4 + 1][r] = v.y;                      \
        a_s[kq * 4 + 2][r] = v.z; a_s[kq * 4 + 3][r] = v.w;                      \
        _Pragma("unroll")                                                        \
        for (int s = 0; s < 2; s++) {                                            \
          const int fi = tid + s * NT;                                           \
          const int rb = fi >> 3, kb = fi & 7;                                   \
          const float4 w = *(const float4*)(E + (size_t)(col0 + rb) * DIM + (k0 + kb * 4)); \
          b_s[kb * 4 + 0][rb] = w.x; b_s[kb * 4 + 1][rb] = w.y;                  \
          b_s[kb * 4 + 2][rb] = w.z; b_s[kb * 4 + 3][rb] = w.w;                  \
        }                                                                        \
      }                                                                          \
      __syncthreads();                                                           \
      _Pragma("unroll")                                                          \
      for (int k = 0; k < BK; k++) {                                             \
        const float2 a2 = *(const float2*)&a_s[k][ty * 2];                       \
        float br[8];                                                             \
        *(float4*)(br)     = *(const float4*)&b_s[k][tx * 8];                    \
        *(float4*)(br + 4) = *(const float4*)&b_s[k][tx * 8 + 4];                \
        _Pragma("unroll")                                                        \
        for (int j = 0; j < 8; j++) {                                            \
          ACC[0][j] = fmaf(a2.x, br[j], ACC[0][j]);                              \
          ACC[1][j] = fmaf(a2.y, br[j], ACC[1][j]);                              \
        }                                                                        \
      }                                                                          \
    }

  for (int ct = 0; ct < NTOK / BN; ++ct) {
    const int col0 = ct * BN;

    float accA[2][8], accB[2][8];
#pragma unroll
    for (int i = 0; i < 2; i++)
#pragma unroll
      for (int j = 0; j < 8; j++) { accA[i][j] = 0.f; accB[i][j] = 0.f; }

    for (int k0 = 0; k0 < KSPLIT; k0 += BK) GEMM_STEP(k0, accA)
    for (int k0 = KSPLIT; k0 < DIM; k0 += BK) GEMM_STEP(k0, accB)

    float e2v[8];
    *(float4*)(e2v)     = *(const float4*)(e2 + col0 + tx * 8);
    *(float4*)(e2v + 4) = *(const float4*)(e2 + col0 + tx * 8 + 4);
#pragma unroll
    for (int i = 0; i < 2; i++) {
#pragma unroll
      for (int j = 0; j < 8; j++) {
        const float dot = accA[i][j] + accB[i][j];
        const float se = x2r[i] + e2v[j];
        const float d = fmaf(-2.0f, dot, se);
        const int ci = col0 + tx * 8 + j;
        ins4(bv[i], bi[i], d, ci);
      }
    }
  }
#undef GEMM_STEP

#pragma unroll
  for (int m = 1; m < 16; m <<= 1) {
#pragma unroll
    for (int i = 0; i < 2; i++) {
      float ov[4]; int oi[4];
#pragma unroll
      for (int c = 0; c < 4; c++) {
        ov[c] = __shfl_xor(bv[i][c], m, 64);
        oi[c] = __shfl_xor(bi[i][c], m, 64);
      }
#pragma unroll
      for (int c = 0; c < 4; c++) ins4(bv[i], bi[i], ov[c], oi[c]);
    }
  }

#pragma unroll
  for (int i = 0; i < 2; i++) {
    if (tx == i) {
      const int gr = row0 + ty * 2 + i;
      out[EI_OFF + gr] = (float)bi[i][0];
      const double d1 = (double)bv[i][1], d2 = (double)bv[i][2], d3 = (double)bv[i][3];
      double nrm = sqrt(d1 * d1 + d2 * d2 + d3 * d3);
      nrm = fmax(nrm, 1e-12);
      const double t1 = 1.0 / (d1 / nrm + 1e-4);
      const double t2 = 1.0 / (d2 / nrm + 1e-4);
      const double t3 = 1.0 / (d3 / nrm + 1e-4);
      const double mx = fmax(t1, fmax(t2, t3));
      const double e1 = exp(t1 - mx), e2x = exp(t2 - mx), e3 = exp(t3 - mx);
      const double s = e1 + e2x + e3;
      out[TV_OFF + gr * 3 + 0] = (float)(e1 / s);
      out[TV_OFF + gr * 3 + 1] = (float)(e2x / s);
      out[TV_OFF + gr * 3 + 2] = (float)(e3 / s);
      out[TI_OFF + gr * 3 + 0] = (float)bi[i][1];
      out[TI_OFF + gr * 3 + 1] = (float)bi[i][2];
      out[TI_OFF + gr * 3 + 2] = (float)bi[i][3];
    }
  }

  __syncthreads();
  int* idx_sh = (int*)&a_s[0][0];
  if (tx == 0) idx_sh[ty * 2 + 0] = bi[0][0];
  if (tx == 1) idx_sh[ty * 2 + 1] = bi[1][0];
  __syncthreads();

  for (int f = tid; f < BM * (DIM / 4); f += NT) {
    const int r = f / (DIM / 4);
    const int c = f % (DIM / 4);
    const int e = idx_sh[r];
    const float4 v = *(const float4*)(E + (size_t)e * DIM + c * 4);
    *(float4*)(out + Q_OFF + (size_t)(row0 + r) * DIM + c * 4) = v;
  }
}

// ---------------------------------------------------------------- launch
extern "C" void kernel_launch(void* const* d_in, const int* in_sizes, int n_in,
                              void* d_out, int out_size, void* d_ws, size_t ws_size,
                              hipStream_t stream) {
  const float* x = (const float*)d_in[0];  // inputs_flatten [32768,768]
  const float* E = (const float*)d_in[1];  // embed          [8192,768]
  float* out = (float*)d_out;

  // ws layout (bytes) — identical footprint to R5/R6 (proven to fit)
  unsigned char* ws = (unsigned char*)d_ws;
  float* e2 = (float*)ws;                                   // 8192 f32
  float* x2 = (float*)(ws + 32768);                         // 32768 f32
  unsigned short* topp = (unsigned short*)(ws + 32768 + 131072);  // 32768*16 u16 = 1MB
  unsigned short* xbT = (unsigned short*)(ws + 32768 + 131072 + 1048576);
  unsigned short* ebT = xbT + (size_t)NROWS * DIM;
  const size_t need = 32768 + 131072 + 1048576 +
                      (size_t)NROWS * DIM * 2 + (size_t)NTOK * DIM * 2;

  np_norm_kernel<<<NTOK / 4, 256, 0, stream>>>(E, e2);
  np_norm_kernel<<<NROWS / 4, 256, 0, stream>>>(x, x2);

  if (ws_size >= need) {
    cvtT_kernel<<<dim3(NROWS / 256, DIM / 8), 256, 0, stream>>>(x, xbT, NROWS);
    cvtT_kernel<<<dim3(NTOK / 256, DIM / 8), 256, 0, stream>>>(E, ebT, NTOK);
    vq_rank<<<256, 512, 0, stream>>>(xbT, ebT, e2, topp);
    vq_refine16<<<NROWS * 16 / 256, 256, 0, stream>>>(x, E, x2, e2, topp, out);
  } else {
    vq_main<<<NROWS / BM, NT, 0, stream>>>(x, E, x2, e2, out);
  }
}